// Round 1
// baseline (478.059 us; speedup 1.0000x reference)
//
#include <hip/hip_runtime.h>

typedef _Float16 f16;
typedef f16 f16x8 __attribute__((ext_vector_type(8)));
typedef float f32x4 __attribute__((ext_vector_type(4)));

#define MFMA(a,b,c) __builtin_amdgcn_mfma_f32_16x16x32_f16((a),(b),(c),0,0,0)

static constexpr int B_ = 4, C_ = 256, A_ = 4096;
static constexpr int CA   = C_ * A_;        // 1048576
static constexpr int BCA  = B_ * CA;        // 4194304
static constexpr int OUT_T = B_ * 2 * CA;   // 8388608 floats per output tensor
// workspace layout (units: halfs)
static constexpr size_t WS_Va16 = 0;                       // c-major fp16 Va
static constexpr size_t WS_Vb16 = WS_Va16 + (size_t)BCA;   // c-major fp16 Vb
static constexpr size_t WS_VaT  = WS_Vb16 + (size_t)BCA;   // a-major fp16 Va^T
static constexpr size_t WS_VbT  = WS_VaT  + (size_t)BCA;   // a-major fp16 Vb^T
static constexpr size_t WS_Q1   = WS_VbT  + (size_t)BCA;   // a-major fp16 Q1 = Va_corr
static constexpr size_t WS_W16  = WS_Q1   + (size_t)BCA;   // fp16 W_linear [d][c]
static constexpr size_t WS_HALFS = WS_W16 + (size_t)(C_ * C_);

// ---------------- kernel 1: W_linear fp32 -> fp16 ----------------
__global__ void coatt_convw(const float* __restrict__ W, f16* __restrict__ W16) {
    int i = blockIdx.x * 256 + threadIdx.x;   // grid 256 -> 65536 elems
    W16[i] = (f16)W[i];
}

// ---------------- kernel 2: convert + transpose Va, Vb ----------------
// grid (A/64, C/64, B*2); produces c-major fp16 copy and a-major fp16 transpose
__global__ void coatt_transpose(const float* __restrict__ Va,
                                const float* __restrict__ Vb,
                                f16* __restrict__ ws) {
    __shared__ f16 tile[64][72];  // [c_local][a_local], padded
    int z = blockIdx.z; int b = z >> 1; int which = z & 1;
    const float* src = which ? Vb : Va;
    f16* cm = ws + (which ? WS_Vb16 : WS_Va16);
    f16* am = ws + (which ? WS_VbT  : WS_VaT);
    int a0 = blockIdx.x * 64, c0 = blockIdx.y * 64;
    int t = threadIdx.x;
    int r = t >> 2, q = t & 3;   // r: row 0..63, q: 16-col chunk 0..3

    const float* sp = src + (size_t)(b * C_ + c0 + r) * A_ + a0 + q * 16;
    f16 h[16] __attribute__((aligned(16)));
#pragma unroll
    for (int i = 0; i < 4; ++i) {
        float4 v = *(const float4*)(sp + i * 4);
        h[i*4+0] = (f16)v.x; h[i*4+1] = (f16)v.y;
        h[i*4+2] = (f16)v.z; h[i*4+3] = (f16)v.w;
    }
    f16* cp = cm + (size_t)(b * C_ + c0 + r) * A_ + a0 + q * 16;
    *(f16x8*)(cp)     = *(const f16x8*)&h[0];
    *(f16x8*)(cp + 8) = *(const f16x8*)&h[8];
#pragma unroll
    for (int i = 0; i < 16; ++i) tile[r][q * 16 + i] = h[i];
    __syncthreads();
    f16 ht[16] __attribute__((aligned(16)));
#pragma unroll
    for (int i = 0; i < 16; ++i) ht[i] = tile[q * 16 + i][r];  // [c][a] -> transposed
    f16* ap = am + (size_t)(b * A_ + a0 + r) * C_ + c0 + q * 16;
    *(f16x8*)(ap)     = *(const f16x8*)&ht[0];
    *(f16x8*)(ap + 8) = *(const f16x8*)&ht[8];
}

// ---------------- kernel 3: Q1[a,d] = sum_c VaT[a,c] * W[d,c] ----------------
// grid (A/64, B); block 256 (4 waves, 16 a-rows each)
__global__ __launch_bounds__(256) void coatt_q1(const f16* __restrict__ vat,
                                                const f16* __restrict__ w16,
                                                f16* __restrict__ q1) {
    int b = blockIdx.y; int a0 = blockIdx.x * 64;
    int tid = threadIdx.x, wave = tid >> 6, lane = tid & 63;
    int m = lane & 15, quad = lane >> 4;

    const f16* Ap = vat + (size_t)(b * A_ + a0 + wave * 16 + m) * C_ + quad * 8;
    f16x8 af[8];
#pragma unroll
    for (int kc = 0; kc < 8; ++kc) af[kc] = *(const f16x8*)(Ap + kc * 32);

    f32x4 acc[16];
#pragma unroll
    for (int t = 0; t < 16; ++t) acc[t] = (f32x4){0.f, 0.f, 0.f, 0.f};

#pragma unroll
    for (int kc = 0; kc < 8; ++kc) {
#pragma unroll
        for (int t = 0; t < 16; ++t) {
            f16x8 bf = *(const f16x8*)(w16 + (size_t)(t * 16 + m) * C_ + kc * 32 + quad * 8);
            acc[t] = MFMA(af[kc], bf, acc[t]);
        }
    }
    // C-layout: col d = 16t+m, row a = quad*4+r (within the wave's 16)
#pragma unroll
    for (int t = 0; t < 16; ++t) {
#pragma unroll
        for (int r = 0; r < 4; ++r) {
            int arow = a0 + wave * 16 + quad * 4 + r;
            q1[(size_t)(b * A_ + arow) * C_ + t * 16 + m] = (f16)acc[t][r];
        }
    }
}

// ---------------- kernel 4: dual flash attention + gate + store ----------------
// grid (A/64, B, 2); block 256 (4 waves * 16 query rows). Bc = 32 keys/iter.
__global__ __launch_bounds__(256) void coatt_flash(const f16* __restrict__ ws,
                                                   const float* __restrict__ Wgate,
                                                   float* __restrict__ dout) {
    __shared__ __align__(16) char smem[42496];
    f16* Klds = (f16*)smem;                   // [32][264]  16896 B
    f16* Vlds = (f16*)(smem + 16896);         // [256][40]  20480 B
    f16* Plds = (f16*)(smem + 37376);         // [4][16][40] 5120 B
    float* Olds = (float*)smem;               // epilogue reuse [128][68] 34816 B

    int att = blockIdx.z, b = blockIdx.y;
    int n0 = blockIdx.x * 64;
    const f16 *Qp, *Kp, *Vp; float* outp;
    if (att == 0) {   // -> Vb_att (softmax over a of S[n,a]); V = Va^T
        Qp = ws + WS_Q1  + (size_t)b * CA;
        Kp = ws + WS_VbT + (size_t)b * CA;
        Vp = ws + WS_Va16 + (size_t)b * CA;   // c-major: V[key][c] = Va16[c][key]
        outp = dout + (size_t)OUT_T + (size_t)b * 2 * CA;
    } else {          // -> Va_att (softmax over a of S[a,n]); V = Vb^T
        Qp = ws + WS_VbT + (size_t)b * CA;
        Kp = ws + WS_Q1  + (size_t)b * CA;
        Vp = ws + WS_Vb16 + (size_t)b * CA;
        outp = dout + (size_t)b * 2 * CA;
    }

    int tid = threadIdx.x, wave = tid >> 6, lane = tid & 63;
    int m = lane & 15, quad = lane >> 4;

    // Q fragments in registers (A-layout: A[m][k=quad*8+j])
    f16x8 qf[8];
    const f16* qrow = Qp + (size_t)(n0 + wave * 16 + m) * C_ + quad * 8;
#pragma unroll
    for (int kc = 0; kc < 8; ++kc) qf[kc] = *(const f16x8*)(qrow + kc * 32);

    f32x4 Oacc[16];
#pragma unroll
    for (int t = 0; t < 16; ++t) Oacc[t] = (f32x4){0.f, 0.f, 0.f, 0.f};
    float mrow[4], lrow[4];
#pragma unroll
    for (int r = 0; r < 4; ++r) { mrow[r] = -1e30f; lrow[r] = 0.f; }

    for (int kb = 0; kb < 128; ++kb) {
        int key0 = kb * 32;
        // stage K tile [32 keys][256 feat] (a-major rows, 16B chunks)
#pragma unroll
        for (int i = 0; i < 4; ++i) {
            int ci = tid + i * 256;            // 1024 chunks
            int row = ci >> 5, col = (ci & 31) * 8;
            *(f16x8*)(Klds + row * 264 + col) =
                *(const f16x8*)(Kp + (size_t)(key0 + row) * C_ + col);
        }
        // stage V transposed [256 c][32 keys] from c-major source
#pragma unroll
        for (int i = 0; i < 4; ++i) {
            int ci = tid + i * 256;            // 1024 chunks
            int row = ci >> 2, col = (ci & 3) * 8;
            *(f16x8*)(Vlds + row * 40 + col) =
                *(const f16x8*)(Vp + (size_t)row * A_ + key0 + col);
        }
        __syncthreads();

        // S tile: 16 queries x 32 keys per wave
        f32x4 Sc[2];
        Sc[0] = (f32x4){0.f,0.f,0.f,0.f}; Sc[1] = (f32x4){0.f,0.f,0.f,0.f};
#pragma unroll
        for (int kc = 0; kc < 8; ++kc) {
#pragma unroll
            for (int jt = 0; jt < 2; ++jt) {
                f16x8 kf = *(const f16x8*)(Klds + (jt * 16 + m) * 264 + kc * 32 + quad * 8);
                Sc[jt] = MFMA(qf[kc], kf, Sc[jt]);
            }
        }

        // online softmax (rows owned: quad*4+r; stats shared across 16-lane group)
        float alpha[4];
#pragma unroll
        for (int r = 0; r < 4; ++r) {
            float mx = fmaxf(Sc[0][r], Sc[1][r]);
            mx = fmaxf(mx, __shfl_xor(mx, 1));
            mx = fmaxf(mx, __shfl_xor(mx, 2));
            mx = fmaxf(mx, __shfl_xor(mx, 4));
            mx = fmaxf(mx, __shfl_xor(mx, 8));
            float mn = fmaxf(mrow[r], mx);
            float al = __expf(mrow[r] - mn);
            mrow[r] = mn; alpha[r] = al;
            float p0 = __expf(Sc[0][r] - mn);
            float p1 = __expf(Sc[1][r] - mn);
            float s = p0 + p1;
            s += __shfl_xor(s, 1); s += __shfl_xor(s, 2);
            s += __shfl_xor(s, 4); s += __shfl_xor(s, 8);
            lrow[r] = lrow[r] * al + s;
            // P -> LDS (C-layout -> A-layout round trip, wave-private)
            Plds[wave * 640 + (quad * 4 + r) * 40 + m]      = (f16)p0;
            Plds[wave * 640 + (quad * 4 + r) * 40 + 16 + m] = (f16)p1;
        }
#pragma unroll
        for (int t = 0; t < 16; ++t) {
#pragma unroll
            for (int r = 0; r < 4; ++r) Oacc[t][r] *= alpha[r];
        }
        // PV: O[16 x 256] += P[16 x 32] * V[32 x 256]
        f16x8 pf = *(const f16x8*)(Plds + wave * 640 + m * 40 + quad * 8);
#pragma unroll
        for (int t = 0; t < 16; ++t) {
            f16x8 vf = *(const f16x8*)(Vlds + (t * 16 + m) * 40 + quad * 8);
            Oacc[t] = MFMA(pf, vf, Oacc[t]);
        }
        __syncthreads();
    }

    // epilogue: 1/l, gate dot, sigmoid mask, scale
    float inv[4];
#pragma unroll
    for (int r = 0; r < 4; ++r) inv[r] = 1.0f / lrow[r];
    float g[4] = {0.f, 0.f, 0.f, 0.f};
#pragma unroll
    for (int t = 0; t < 16; ++t) {
        float w = Wgate[t * 16 + m];
#pragma unroll
        for (int r = 0; r < 4; ++r) {
            float o = Oacc[t][r] * inv[r];
            Oacc[t][r] = o;
            g[r] += o * w;
        }
    }
    float mask[4];
#pragma unroll
    for (int r = 0; r < 4; ++r) {
        float s = g[r];
        s += __shfl_xor(s, 1); s += __shfl_xor(s, 2);
        s += __shfl_xor(s, 4); s += __shfl_xor(s, 8);
        mask[r] = 1.0f / (1.0f + __expf(-s));
    }
#pragma unroll
    for (int t = 0; t < 16; ++t) {
#pragma unroll
        for (int r = 0; r < 4; ++r) Oacc[t][r] *= mask[r];
    }

    // transpose O through LDS for coalesced c-major stores (2 halves of 128 c)
#pragma unroll
    for (int hf = 0; hf < 2; ++hf) {
        __syncthreads();
#pragma unroll
        for (int tt = 0; tt < 8; ++tt) {
            int t = hf * 8 + tt;
#pragma unroll
            for (int r = 0; r < 4; ++r)
                Olds[(tt * 16 + m) * 68 + wave * 16 + quad * 4 + r] = Oacc[t][r];
        }
        __syncthreads();
#pragma unroll
        for (int i = 0; i < 8; ++i) {
            int ci = tid + i * 256;       // 2048 float4 chunks
            int c = ci >> 4, ch = (ci & 15) * 4;
            float4 v = *(const float4*)(Olds + c * 68 + ch);
            *(float4*)(outp + (size_t)(hf * 128 + c) * A_ + n0 + ch) = v;
        }
    }
}

// ---------------- kernel 5: raw-input concat halves + scalar ----------------
__global__ void coatt_copy(const float* __restrict__ Va, const float* __restrict__ Vb,
                           const int* __restrict__ psz, float* __restrict__ dout) {
    int base = blockIdx.x * 256 + threadIdx.x;   // grid 2048 -> 524288 threads
    const float4* va4 = (const float4*)Va;
    const float4* vb4 = (const float4*)Vb;
    float4* out4 = (float4*)dout;
#pragma unroll
    for (int i = 0; i < 4; ++i) {
        int idx = base + i * 524288;             // float4 index 0..2097151
        int t = idx >> 20;                       // tensor
        int r = idx & 1048575;                   // f4 idx within tensor (b*262144+rr)
        int b = r >> 18;
        int rr = r & 262143;
        float4 v = t ? vb4[r] : va4[r];
        out4[(size_t)t * 2097152 + (size_t)b * 524288 + 262144 + rr] = v;
    }
    if (base == 0) dout[16777216] = (float)(*psz);
}

extern "C" void kernel_launch(void* const* d_in, const int* in_sizes, int n_in,
                              void* d_out, int out_size, void* d_ws, size_t ws_size,
                              hipStream_t stream) {
    const float* Va = (const float*)d_in[0];
    const float* Vb = (const float*)d_in[1];
    const float* Wl = (const float*)d_in[2];
    const float* Wg = (const float*)d_in[3];
    const int* psz  = (const int*)d_in[4];
    float* out = (float*)d_out;
    f16* ws = (f16*)d_ws;

    if (ws_size < WS_HALFS * sizeof(f16)) return;  // need ~42 MB scratch

    coatt_convw<<<256, 256, 0, stream>>>(Wl, ws + WS_W16);
    coatt_transpose<<<dim3(64, 4, 8), 256, 0, stream>>>(Va, Vb, ws);
    coatt_q1<<<dim3(64, 4), 256, 0, stream>>>(ws + WS_VaT, ws + WS_W16, ws + WS_Q1);
    coatt_flash<<<dim3(64, 4, 2), 256, 0, stream>>>(ws, Wg, out);
    coatt_copy<<<2048, 256, 0, stream>>>(Va, Vb, psz, out);
}